// Round 6
// baseline (465.704 us; speedup 1.0000x reference)
//
#include <hip/hip_runtime.h>

#define N_RELS 16
#define N_BASES 8
#define HD 128
#define SCAN_B 1024
#define ROWS 32

typedef __attribute__((ext_vector_type(8))) short bf16x8;
typedef __attribute__((ext_vector_type(4))) float floatx4;

__device__ __forceinline__ short bf16rn(float f) {
    union { float f; unsigned u; } v; v.f = f;
    unsigned u = v.u;
    unsigned r = (u + 0x7fffu + ((u >> 16) & 1u)) >> 16;
    return (short)r;
}

// ---------------- dst counting-sort: hist -> scan -> scatter (CSR) ----------------

__global__ void hist_dst(const int* __restrict__ dst, int E, int* __restrict__ cnt) {
    int i = blockIdx.x * blockDim.x + threadIdx.x;
    if (i < E) atomicAdd(&cnt[dst[i]], 1);
}

__global__ void scan_partial(const int* __restrict__ cnt, int N,
                             int* __restrict__ excl, int* __restrict__ bsum) {
    __shared__ int s[SCAN_B];
    int t = threadIdx.x, i = blockIdx.x * SCAN_B + t;
    int v = (i < N) ? cnt[i] : 0;
    s[t] = v; __syncthreads();
    for (int o = 1; o < SCAN_B; o <<= 1) {
        int x = (t >= o) ? s[t - o] : 0;
        __syncthreads();
        s[t] += x;
        __syncthreads();
    }
    if (i < N) excl[i] = s[t] - v;
    if (t == SCAN_B - 1) bsum[blockIdx.x] = s[t];
}

__global__ void scan_bsum(int* __restrict__ bsum, int nb, int* __restrict__ row_ptr,
                          int N, int E) {
    if (threadIdx.x == 0 && blockIdx.x == 0) {
        int run = 0;
        for (int b = 0; b < nb; b++) { int x = bsum[b]; bsum[b] = run; run += x; }
        row_ptr[N] = E;
    }
}

__global__ void scan_fixup(int* __restrict__ row_ptr, const int* __restrict__ bsum,
                           int N, int* __restrict__ cursor) {
    int i = blockIdx.x * blockDim.x + threadIdx.x;
    if (i < N) { int v = row_ptr[i] + bsum[i >> 10]; row_ptr[i] = v; cursor[i] = v; }
}

// pack (etype, src) into one int: src < 65536
__global__ void scatter_dst(const int* __restrict__ dst, const int* __restrict__ src,
                            const int* __restrict__ et, const float* __restrict__ norm,
                            int E, int* __restrict__ cursor, int2* __restrict__ edata) {
    int i = blockIdx.x * blockDim.x + threadIdx.x;
    if (i >= E) return;
    int p = atomicAdd(&cursor[dst[i]], 1);
    edata[p] = make_int2((et[i] << 16) | src[i], __float_as_int(norm[i]));
}

// ---------------- pack fp32 rows -> bf16 pairs (one uint = 2 cols) ----------------

__global__ void pack_bf16(const float* __restrict__ x, unsigned* __restrict__ o, int n2) {
    int i = blockIdx.x * blockDim.x + threadIdx.x;
    if (i >= n2) return;
    float2 v = ((const float2*)x)[i];
    o[i] = ((unsigned)(unsigned short)bf16rn(v.y) << 16) | (unsigned short)bf16rn(v.x);
}

// ---------------- V[l][b] -> MFMA B-frag order, bf16 ----------------
// frag: lane holds B[n=lane&15][k=(lane>>4)*8+j]; idx = ((kk*8+t)*64+lane)*8+j

__global__ void compute_V_frags(const float* __restrict__ V1, const float* __restrict__ V2,
                                short* __restrict__ Vf) {
    int blk = blockIdx.x;          // 0..15 = layer*8 + basis
    const float* V = ((blk & 8) ? V2 : V1) + (size_t)(blk & 7) * 16384;
    size_t obase = (size_t)blk * 16384;
    for (int e = threadIdx.x; e < 16384; e += blockDim.x) {
        float w = V[e];
        int k = e >> 7, n = e & 127;
        int kk = k >> 5, q = (k >> 3) & 3, j = k & 7;
        int lane = q * 16 + (n & 15);
        int idx = ((kk * 8 + (n >> 4)) * 64 + lane) * 8 + j;
        Vf[obase + idx] = bf16rn(w);
    }
}

// ---------------- fused per-tile RGCN layer ----------------
// Block = 32 dst rows, 256 threads (4 waves). Phase A: per-wave 8-node segment-sum of
// coef-weighted bf16 gathers -> Z tile in LDS (MFMA A-frag order, exactly 64 KB).
// Phase B: Z(32x1024) @ V(1024x128) via MFMA; B-frags straight from L2-resident Vf.
// mode 0: store bf16(relu(acc+bias)); mode 1: store fp32(acc+bias).

__global__ __launch_bounds__(256, 2) void rgcn_tile(
    const unsigned* __restrict__ hb, const int2* __restrict__ edata,
    const int* __restrict__ row_ptr, const float* __restrict__ coef,
    const short* __restrict__ Vf, const float* __restrict__ bias,
    void* __restrict__ outp, int N, int mode) {
    __shared__ __align__(16) unsigned Zs[N_BASES][4][4][ROWS][4];  // [b][kk][q][m][ju] 64 KB

    const int tid = threadIdx.x;
    const int wave = tid >> 6, lane = tid & 63;
    const int nb0 = blockIdx.x * ROWS;

    // ---- phase A: lane covers col-pair (2*lane, 2*lane+1); frag coords for writes:
    const int lkk = lane >> 4, lq = (lane >> 2) & 3, lju = lane & 3;

    for (int i = 0; i < 8; i++) {
        const int row = wave * 8 + i;
        const int node = nb0 + row;
        int e = 0, end = 0;
        if (node < N) { e = row_ptr[node]; end = row_ptr[node + 1]; }

        float2 acc[N_BASES] = {};
        auto proc = [&](int2 m, unsigned g) {
            int ets = __builtin_amdgcn_readfirstlane(m.x >> 16);   // et wave-uniform
            float nv = __int_as_float(m.y);
            const float* cw = coef + ets * N_BASES;                // scalar loads
            float vx = __uint_as_float(g << 16);
            float vy = __uint_as_float(g & 0xffff0000u);
#pragma unroll
            for (int b = 0; b < N_BASES; b++) {
                float w = cw[b] * nv;
                acc[b].x = fmaf(vx, w, acc[b].x);
                acc[b].y = fmaf(vy, w, acc[b].y);
            }
        };

        for (; e + 4 <= end; e += 4) {
            int2 m0 = edata[e], m1 = edata[e + 1], m2 = edata[e + 2], m3 = edata[e + 3];
            unsigned g0 = hb[(size_t)(m0.x & 0xffff) * 64 + lane];
            unsigned g1 = hb[(size_t)(m1.x & 0xffff) * 64 + lane];
            unsigned g2 = hb[(size_t)(m2.x & 0xffff) * 64 + lane];
            unsigned g3 = hb[(size_t)(m3.x & 0xffff) * 64 + lane];
            proc(m0, g0); proc(m1, g1); proc(m2, g2); proc(m3, g3);
        }
        for (; e < end; e++) {
            int2 m = edata[e];
            unsigned g = hb[(size_t)(m.x & 0xffff) * 64 + lane];
            proc(m, g);
        }

#pragma unroll
        for (int b = 0; b < N_BASES; b++) {
            unsigned lo = (unsigned)(unsigned short)bf16rn(acc[b].x);
            unsigned hi = (unsigned)(unsigned short)bf16rn(acc[b].y);
            Zs[b][lkk][lq][row][lju] = (hi << 16) | lo;    // zero rows for node>=N too
        }
    }
    __syncthreads();

    // ---- phase B: wave handles t-tiles {2w, 2w+1}, m-tiles {0,1}
    const int q = lane >> 4, cc = lane & 15;
    const int tt = wave * 2;
    floatx4 ac00 = {}, ac01 = {}, ac10 = {}, ac11 = {};

#pragma unroll 2
    for (int b = 0; b < N_BASES; b++) {
#pragma unroll
        for (int kk = 0; kk < 4; kk++) {
            bf16x8 a0 = *(const bf16x8*)&Zs[b][kk][q][cc][0];
            bf16x8 a1 = *(const bf16x8*)&Zs[b][kk][q][16 + cc][0];
            const short* vb = Vf + (size_t)b * 16384 + ((size_t)(kk * 8 + tt) * 64 + lane) * 8;
            bf16x8 B0 = *(const bf16x8*)vb;
            bf16x8 B1 = *(const bf16x8*)(vb + 512);
            ac00 = __builtin_amdgcn_mfma_f32_16x16x32_bf16(a0, B0, ac00, 0, 0, 0);
            ac01 = __builtin_amdgcn_mfma_f32_16x16x32_bf16(a0, B1, ac01, 0, 0, 0);
            ac10 = __builtin_amdgcn_mfma_f32_16x16x32_bf16(a1, B0, ac10, 0, 0, 0);
            ac11 = __builtin_amdgcn_mfma_f32_16x16x32_bf16(a1, B1, ac11, 0, 0, 0);
        }
    }

    // ---- epilogue: C/D layout col = tt*16+cc, row(m) = q*4+i
    float bv0 = bias[tt * 16 + cc], bv1 = bias[(tt + 1) * 16 + cc];
    if (mode == 0) {
        unsigned short* o = (unsigned short*)outp;
#pragma unroll
        for (int mi = 0; mi < 2; mi++) {
            const floatx4& c0 = mi ? ac10 : ac00;
            const floatx4& c1 = mi ? ac11 : ac01;
#pragma unroll
            for (int i = 0; i < 4; i++) {
                int node = nb0 + mi * 16 + q * 4 + i;
                if (node < N) {
                    float v0 = fmaxf(c0[i] + bv0, 0.f);
                    float v1 = fmaxf(c1[i] + bv1, 0.f);
                    o[(size_t)node * HD + tt * 16 + cc] = (unsigned short)bf16rn(v0);
                    o[(size_t)node * HD + (tt + 1) * 16 + cc] = (unsigned short)bf16rn(v1);
                }
            }
        }
    } else {
        float* o = (float*)outp;
#pragma unroll
        for (int mi = 0; mi < 2; mi++) {
            const floatx4& c0 = mi ? ac10 : ac00;
            const floatx4& c1 = mi ? ac11 : ac01;
#pragma unroll
            for (int i = 0; i < 4; i++) {
                int node = nb0 + mi * 16 + q * 4 + i;
                if (node < N) {
                    o[(size_t)node * HD + tt * 16 + cc] = c0[i] + bv0;
                    o[(size_t)node * HD + (tt + 1) * 16 + cc] = c1[i] + bv1;
                }
            }
        }
    }
}

// ---------------- launch ----------------

extern "C" void kernel_launch(void* const* d_in, const int* in_sizes, int n_in,
                              void* d_out, int out_size, void* d_ws, size_t ws_size,
                              hipStream_t stream) {
    const float* h     = (const float*)d_in[0];
    const float* norm  = (const float*)d_in[1];
    const int*   src   = (const int*)d_in[2];
    const int*   dst   = (const int*)d_in[3];
    const int*   etype = (const int*)d_in[4];
    const float* V1    = (const float*)d_in[5];
    const float* coef1 = (const float*)d_in[6];
    const float* bias1 = (const float*)d_in[7];
    const float* V2    = (const float*)d_in[8];
    const float* coef2 = (const float*)d_in[9];
    const float* bias2 = (const float*)d_in[10];
    const int N = in_sizes[0] / HD;   // 50000
    const int E = in_sizes[2];        // 640000
    float* out = (float*)d_out;
    (void)n_in; (void)out_size; (void)ws_size;

    char* ws = (char*)d_ws;
    size_t off = 0;
    auto alloc = [&](size_t bytes) {
        void* p = ws + off;
        off += (bytes + 255) & ~(size_t)255;
        return p;
    };
    short*    Vf      = (short*)alloc((size_t)16 * 16384 * sizeof(short));   // 512 KB
    unsigned* hb      = (unsigned*)alloc((size_t)N * 64 * sizeof(unsigned)); // 12.8 MB
    unsigned* h1b     = (unsigned*)alloc((size_t)N * 64 * sizeof(unsigned)); // 12.8 MB
    int2*     edata   = (int2*)alloc((size_t)E * sizeof(int2));
    int*      cnt     = (int*)alloc((size_t)N * sizeof(int));
    int*      row_ptr = (int*)alloc((size_t)(N + 1) * sizeof(int));
    int*      cursor  = (int*)alloc((size_t)N * sizeof(int));
    int*      bsum    = (int*)alloc(256 * sizeof(int));

    const int nb = (N + SCAN_B - 1) / SCAN_B;

    hipMemsetAsync(cnt, 0, (size_t)N * sizeof(int), stream);
    hist_dst<<<(E + 255) / 256, 256, 0, stream>>>(dst, E, cnt);
    scan_partial<<<nb, SCAN_B, 0, stream>>>(cnt, N, row_ptr, bsum);
    scan_bsum<<<1, 64, 0, stream>>>(bsum, nb, row_ptr, N, E);
    scan_fixup<<<(N + 255) / 256, 256, 0, stream>>>(row_ptr, bsum, N, cursor);
    scatter_dst<<<(E + 255) / 256, 256, 0, stream>>>(dst, src, etype, norm, E, cursor, edata);
    compute_V_frags<<<16, 256, 0, stream>>>(V1, V2, Vf);
    pack_bf16<<<(N * 64 + 255) / 256, 256, 0, stream>>>(h, hb, N * 64);

    const int tiles = (N + ROWS - 1) / ROWS;   // 1563

    // layer 1: h1b = bf16(relu(bias1 + Z @ V1))
    rgcn_tile<<<tiles, 256, 0, stream>>>(hb, edata, row_ptr, coef1, Vf, bias1, h1b, N, 0);
    // layer 2: out = bias2 + Z(h1b) @ V2
    rgcn_tile<<<tiles, 256, 0, stream>>>(h1b, edata, row_ptr, coef2, Vf + (size_t)8 * 16384,
                                         bias2, out, N, 1);
}

// Round 7
// 363.266 us; speedup vs baseline: 1.2820x; 1.2820x over previous
//
#include <hip/hip_runtime.h>

#define N_RELS 16
#define N_BASES 8
#define HD 128
#define SCAN_B 1024
#define ROWS 32

typedef __attribute__((ext_vector_type(8))) short bf16x8;
typedef __attribute__((ext_vector_type(4))) float floatx4;

__device__ __forceinline__ short bf16rn(float f) {
    union { float f; unsigned u; } v; v.f = f;
    unsigned u = v.u;
    unsigned r = (u + 0x7fffu + ((u >> 16) & 1u)) >> 16;
    return (short)r;
}

// ---------------- dst counting-sort: hist -> scan -> scatter (CSR) ----------------

__global__ void hist_dst(const int* __restrict__ dst, int E, int* __restrict__ cnt) {
    int i = blockIdx.x * blockDim.x + threadIdx.x;
    if (i < E) atomicAdd(&cnt[dst[i]], 1);
}

__global__ void scan_partial(const int* __restrict__ cnt, int N,
                             int* __restrict__ excl, int* __restrict__ bsum) {
    __shared__ int s[SCAN_B];
    int t = threadIdx.x, i = blockIdx.x * SCAN_B + t;
    int v = (i < N) ? cnt[i] : 0;
    s[t] = v; __syncthreads();
    for (int o = 1; o < SCAN_B; o <<= 1) {
        int x = (t >= o) ? s[t - o] : 0;
        __syncthreads();
        s[t] += x;
        __syncthreads();
    }
    if (i < N) excl[i] = s[t] - v;
    if (t == SCAN_B - 1) bsum[blockIdx.x] = s[t];
}

__global__ void scan_bsum(int* __restrict__ bsum, int nb, int* __restrict__ row_ptr,
                          int N, int E) {
    if (threadIdx.x == 0 && blockIdx.x == 0) {
        int run = 0;
        for (int b = 0; b < nb; b++) { int x = bsum[b]; bsum[b] = run; run += x; }
        row_ptr[N] = E;
    }
}

__global__ void scan_fixup(int* __restrict__ row_ptr, const int* __restrict__ bsum,
                           int N, int* __restrict__ cursor) {
    int i = blockIdx.x * blockDim.x + threadIdx.x;
    if (i < N) { int v = row_ptr[i] + bsum[i >> 10]; row_ptr[i] = v; cursor[i] = v; }
}

// pack (etype, src) into one int: src < 65536
__global__ void scatter_dst(const int* __restrict__ dst, const int* __restrict__ src,
                            const int* __restrict__ et, const float* __restrict__ norm,
                            int E, int* __restrict__ cursor, int2* __restrict__ edata) {
    int i = blockIdx.x * blockDim.x + threadIdx.x;
    if (i >= E) return;
    int p = atomicAdd(&cursor[dst[i]], 1);
    edata[p] = make_int2((et[i] << 16) | src[i], __float_as_int(norm[i]));
}

// ---------------- pack fp32 rows -> bf16 pairs (one uint = 2 cols) ----------------

__global__ void pack_bf16(const float* __restrict__ x, unsigned* __restrict__ o, int n2) {
    int i = blockIdx.x * blockDim.x + threadIdx.x;
    if (i >= n2) return;
    float2 v = ((const float2*)x)[i];
    o[i] = ((unsigned)(unsigned short)bf16rn(v.y) << 16) | (unsigned short)bf16rn(v.x);
}

// ---------------- V[l][b] -> MFMA B-frag order, bf16 ----------------
// frag: lane holds B[n=lane&15][k=(lane>>4)*8+j]; idx = ((kk*8+t)*64+lane)*8+j

__global__ void compute_V_frags(const float* __restrict__ V1, const float* __restrict__ V2,
                                short* __restrict__ Vf) {
    int blk = blockIdx.x;          // 0..15 = layer*8 + basis
    const float* V = ((blk & 8) ? V2 : V1) + (size_t)(blk & 7) * 16384;
    size_t obase = (size_t)blk * 16384;
    for (int e = threadIdx.x; e < 16384; e += blockDim.x) {
        float w = V[e];
        int k = e >> 7, n = e & 127;
        int kk = k >> 5, q = (k >> 3) & 3, j = k & 7;
        int lane = q * 16 + (n & 15);
        int idx = ((kk * 8 + (n >> 4)) * 64 + lane) * 8 + j;
        Vf[obase + idx] = bf16rn(w);
    }
}

// ---------------- fused per-tile RGCN layer ----------------
// Block = 32 dst rows, 512 threads (8 waves, 4 nodes/wave). Phase A: segment-sum of
// coef-weighted bf16 gathers -> Z tile in LDS (MFMA A-frag order, m padded 32->33 so
// frag stores hit all 32 banks: strides 528=16, 132=4 mod 32). Phase B:
// Z(32x1024) @ V(1024x128); B-frags straight from L2-resident Vf; wave = 1 t-tile x 2 m.
// mode 0: store bf16(relu(acc+bias)); mode 1: store fp32(acc+bias).

__global__ __launch_bounds__(512, 4) void rgcn_tile(
    const unsigned* __restrict__ hb, const int2* __restrict__ edata,
    const int* __restrict__ row_ptr, const float* __restrict__ coef,
    const short* __restrict__ Vf, const float* __restrict__ bias,
    void* __restrict__ outp, int N, int mode) {
    __shared__ __align__(16) unsigned Zs[N_BASES][4][4][ROWS + 1][4];  // 66 KB

    const int tid = threadIdx.x;
    const int wave = tid >> 6, lane = tid & 63;
    const int nb0 = blockIdx.x * ROWS;

    // phase-A frag coords: lane covers cols 2*lane, 2*lane+1
    const int lkk = lane >> 4, lq = (lane >> 2) & 3, lju = lane & 3;

    for (int i = 0; i < 4; i++) {
        const int row = wave * 4 + i;
        const int node = nb0 + row;
        int e = 0, end = 0;
        if (node < N) { e = row_ptr[node]; end = row_ptr[node + 1]; }

        float2 acc[N_BASES] = {};
        auto proc = [&](int2 m, unsigned g) {
            int ets = __builtin_amdgcn_readfirstlane(m.x >> 16);   // et wave-uniform
            float nv = __int_as_float(m.y);
            const float* cw = coef + ets * N_BASES;                // scalar loads
            float vx = __uint_as_float(g << 16) * nv;
            float vy = __uint_as_float(g & 0xffff0000u) * nv;
#pragma unroll
            for (int b = 0; b < N_BASES; b++) {
                float w = cw[b];
                acc[b].x = fmaf(vx, w, acc[b].x);
                acc[b].y = fmaf(vy, w, acc[b].y);
            }
        };

        for (; e + 4 <= end; e += 4) {
            int2 m0 = edata[e], m1 = edata[e + 1], m2 = edata[e + 2], m3 = edata[e + 3];
            unsigned g0 = hb[(size_t)(m0.x & 0xffff) * 64 + lane];
            unsigned g1 = hb[(size_t)(m1.x & 0xffff) * 64 + lane];
            unsigned g2 = hb[(size_t)(m2.x & 0xffff) * 64 + lane];
            unsigned g3 = hb[(size_t)(m3.x & 0xffff) * 64 + lane];
            proc(m0, g0); proc(m1, g1); proc(m2, g2); proc(m3, g3);
        }
        for (; e < end; e++) {
            int2 m = edata[e];
            unsigned g = hb[(size_t)(m.x & 0xffff) * 64 + lane];
            proc(m, g);
        }

#pragma unroll
        for (int b = 0; b < N_BASES; b++) {
            unsigned lo = (unsigned)(unsigned short)bf16rn(acc[b].x);
            unsigned hi = (unsigned)(unsigned short)bf16rn(acc[b].y);
            Zs[b][lkk][lq][row][lju] = (hi << 16) | lo;    // zeros for node>=N too
        }
    }
    __syncthreads();

    // ---- phase B: wave owns t-tile tt=wave, m-tiles {0,1}
    const int q = lane >> 4, cc = lane & 15;
    const int tt = wave;
    floatx4 ac0 = {}, ac1 = {};

#pragma unroll 2
    for (int b = 0; b < N_BASES; b++) {
#pragma unroll
        for (int kk = 0; kk < 4; kk++) {
            bf16x8 a0 = *(const bf16x8*)&Zs[b][kk][q][cc][0];
            bf16x8 a1 = *(const bf16x8*)&Zs[b][kk][q][16 + cc][0];
            bf16x8 B = *(const bf16x8*)(Vf + (size_t)b * 16384 +
                                        ((size_t)(kk * 8 + tt) * 64 + lane) * 8);
            ac0 = __builtin_amdgcn_mfma_f32_16x16x32_bf16(a0, B, ac0, 0, 0, 0);
            ac1 = __builtin_amdgcn_mfma_f32_16x16x32_bf16(a1, B, ac1, 0, 0, 0);
        }
    }

    // ---- epilogue: C/D layout col = tt*16+cc, row(m) = mi*16 + q*4+i
    float bv = bias[tt * 16 + cc];
    if (mode == 0) {
        unsigned short* o = (unsigned short*)outp;
#pragma unroll
        for (int mi = 0; mi < 2; mi++) {
            const floatx4& c = mi ? ac1 : ac0;
#pragma unroll
            for (int i = 0; i < 4; i++) {
                int node = nb0 + mi * 16 + q * 4 + i;
                if (node < N) {
                    float v = fmaxf(c[i] + bv, 0.f);
                    o[(size_t)node * HD + tt * 16 + cc] = (unsigned short)bf16rn(v);
                }
            }
        }
    } else {
        float* o = (float*)outp;
#pragma unroll
        for (int mi = 0; mi < 2; mi++) {
            const floatx4& c = mi ? ac1 : ac0;
#pragma unroll
            for (int i = 0; i < 4; i++) {
                int node = nb0 + mi * 16 + q * 4 + i;
                if (node < N) o[(size_t)node * HD + tt * 16 + cc] = c[i] + bv;
            }
        }
    }
}

// ---------------- launch ----------------

extern "C" void kernel_launch(void* const* d_in, const int* in_sizes, int n_in,
                              void* d_out, int out_size, void* d_ws, size_t ws_size,
                              hipStream_t stream) {
    const float* h     = (const float*)d_in[0];
    const float* norm  = (const float*)d_in[1];
    const int*   src   = (const int*)d_in[2];
    const int*   dst   = (const int*)d_in[3];
    const int*   etype = (const int*)d_in[4];
    const float* V1    = (const float*)d_in[5];
    const float* coef1 = (const float*)d_in[6];
    const float* bias1 = (const float*)d_in[7];
    const float* V2    = (const float*)d_in[8];
    const float* coef2 = (const float*)d_in[9];
    const float* bias2 = (const float*)d_in[10];
    const int N = in_sizes[0] / HD;   // 50000
    const int E = in_sizes[2];        // 640000
    float* out = (float*)d_out;
    (void)n_in; (void)out_size; (void)ws_size;

    char* ws = (char*)d_ws;
    size_t off = 0;
    auto alloc = [&](size_t bytes) {
        void* p = ws + off;
        off += (bytes + 255) & ~(size_t)255;
        return p;
    };
    short*    Vf      = (short*)alloc((size_t)16 * 16384 * sizeof(short));   // 512 KB
    unsigned* hb      = (unsigned*)alloc((size_t)N * 64 * sizeof(unsigned)); // 12.8 MB
    unsigned* h1b     = (unsigned*)alloc((size_t)N * 64 * sizeof(unsigned)); // 12.8 MB
    int2*     edata   = (int2*)alloc((size_t)E * sizeof(int2));
    int*      cnt     = (int*)alloc((size_t)N * sizeof(int));
    int*      row_ptr = (int*)alloc((size_t)(N + 1) * sizeof(int));
    int*      cursor  = (int*)alloc((size_t)N * sizeof(int));
    int*      bsum    = (int*)alloc(256 * sizeof(int));

    const int nb = (N + SCAN_B - 1) / SCAN_B;

    hipMemsetAsync(cnt, 0, (size_t)N * sizeof(int), stream);
    hist_dst<<<(E + 255) / 256, 256, 0, stream>>>(dst, E, cnt);
    scan_partial<<<nb, SCAN_B, 0, stream>>>(cnt, N, row_ptr, bsum);
    scan_bsum<<<1, 64, 0, stream>>>(bsum, nb, row_ptr, N, E);
    scan_fixup<<<(N + 255) / 256, 256, 0, stream>>>(row_ptr, bsum, N, cursor);
    scatter_dst<<<(E + 255) / 256, 256, 0, stream>>>(dst, src, etype, norm, E, cursor, edata);
    compute_V_frags<<<16, 256, 0, stream>>>(V1, V2, Vf);
    pack_bf16<<<(N * 64 + 255) / 256, 256, 0, stream>>>(h, hb, N * 64);

    const int tiles = (N + ROWS - 1) / ROWS;   // 1563

    // layer 1: h1b = bf16(relu(bias1 + Z @ V1))
    rgcn_tile<<<tiles, 512, 0, stream>>>(hb, edata, row_ptr, coef1, Vf, bias1, h1b, N, 0);
    // layer 2: out = bias2 + Z(h1b) @ V2
    rgcn_tile<<<tiles, 512, 0, stream>>>(h1b, edata, row_ptr, coef2, Vf + (size_t)8 * 16384,
                                         bias2, out, N, 1);
}

// Round 8
// 320.520 us; speedup vs baseline: 1.4530x; 1.1334x over previous
//
#include <hip/hip_runtime.h>

#define N_RELS 16
#define N_BASES 8
#define HD 128
#define SCAN_B 1024
#define ROWS 32

typedef __attribute__((ext_vector_type(8))) short bf16x8;
typedef __attribute__((ext_vector_type(4))) float floatx4;
typedef __attribute__((ext_vector_type(2))) float floatx2;

__device__ __forceinline__ short bf16rn(float f) {
    union { float f; unsigned u; } v; v.f = f;
    unsigned u = v.u;
    unsigned r = (u + 0x7fffu + ((u >> 16) & 1u)) >> 16;
    return (short)r;
}

// ---------------- fused setup: pack h->bf16 | V->frags | dst histogram ----------------

__global__ void setup_fused(const float* __restrict__ h, unsigned* __restrict__ hb, int n2,
                            const float* __restrict__ V1, const float* __restrict__ V2,
                            short* __restrict__ Vf,
                            const int* __restrict__ dst, int E, int* __restrict__ cnt,
                            int packBlocks, int vBlocks) {
    int blk = blockIdx.x;
    if (blk < packBlocks) {
        int i = blk * blockDim.x + threadIdx.x;
        if (i < n2) {
            float2 v = ((const float2*)h)[i];
            hb[i] = ((unsigned)(unsigned short)bf16rn(v.y) << 16) | (unsigned short)bf16rn(v.x);
        }
        return;
    }
    blk -= packBlocks;
    if (blk < vBlocks) {
        // frag: lane holds B[n=lane&15][k=(lane>>4)*8+j]; idx = ((kk*8+t)*64+lane)*8+j
        const float* V = ((blk & 8) ? V2 : V1) + (size_t)(blk & 7) * 16384;
        size_t obase = (size_t)blk * 16384;
        for (int e = threadIdx.x; e < 16384; e += blockDim.x) {
            float w = V[e];
            int k = e >> 7, n = e & 127;
            int kk = k >> 5, q = (k >> 3) & 3, j = k & 7;
            int lane = q * 16 + (n & 15);
            int idx = ((kk * 8 + (n >> 4)) * 64 + lane) * 8 + j;
            Vf[obase + idx] = bf16rn(w);
        }
        return;
    }
    blk -= vBlocks;
    int i = blk * blockDim.x + threadIdx.x;
    if (i < E) atomicAdd(&cnt[dst[i]], 1);
}

// ---------------- counting-sort scan (2 kernels) ----------------

__global__ void scan_partial(const int* __restrict__ cnt, int N,
                             int* __restrict__ excl, int* __restrict__ bsum) {
    __shared__ int s[SCAN_B];
    int t = threadIdx.x, i = blockIdx.x * SCAN_B + t;
    int v = (i < N) ? cnt[i] : 0;
    s[t] = v; __syncthreads();
    for (int o = 1; o < SCAN_B; o <<= 1) {
        int x = (t >= o) ? s[t - o] : 0;
        __syncthreads();
        s[t] += x;
        __syncthreads();
    }
    if (i < N) excl[i] = s[t] - v;
    if (t == SCAN_B - 1) bsum[blockIdx.x] = s[t];
}

// adds block-sum prefix (computed in-wave, nb<=64) and inits cursor
__global__ void scan_fixup(int* __restrict__ row_ptr, const int* __restrict__ bsum,
                           int nb, int N, int E, int* __restrict__ cursor) {
    __shared__ int pref[64];
    int t = threadIdx.x;
    if (t < 64) {
        int raw = (t < nb) ? bsum[t] : 0;
        int v = raw;
#pragma unroll
        for (int o = 1; o < 64; o <<= 1) {
            int u = __shfl_up(v, o, 64);
            if (t >= o) v += u;
        }
        pref[t] = v - raw;     // exclusive prefix
    }
    __syncthreads();
    int i = blockIdx.x * blockDim.x + t;
    if (i < N) { int val = row_ptr[i] + pref[i >> 10]; row_ptr[i] = val; cursor[i] = val; }
    if (i == 0) row_ptr[N] = E;
}

// pack (etype, src) into one int: src < 65536
__global__ void scatter_dst(const int* __restrict__ dst, const int* __restrict__ src,
                            const int* __restrict__ et, const float* __restrict__ norm,
                            int E, int* __restrict__ cursor, int2* __restrict__ edata) {
    int i = blockIdx.x * blockDim.x + threadIdx.x;
    if (i >= E) return;
    int p = atomicAdd(&cursor[dst[i]], 1);
    edata[p] = make_int2((et[i] << 16) | src[i], __float_as_int(norm[i]));
}

// ---------------- fused per-tile RGCN layer ----------------
// Block = 32 dst rows, 512 threads (8 waves). Phase A: waves pull nodes from an LDS
// ticket (dynamic balance), segment-sum coef-weighted bf16 gathers with v_pk_fma_f32,
// store Z tile to LDS in MFMA A-frag order (m padded 32->33: stores spread all banks).
// Phase B: Z(32x1024) @ V(1024x128); B-frags from L2-resident Vf; wave = t-tile x 2 m.
// mode 0: store bf16(relu(acc+bias)); mode 1: store fp32(acc+bias).

__global__ __launch_bounds__(512, 4) void rgcn_tile(
    const unsigned* __restrict__ hb, const int2* __restrict__ edata,
    const int* __restrict__ row_ptr, const float* __restrict__ coef,
    const short* __restrict__ Vf, const float* __restrict__ bias,
    void* __restrict__ outp, int N, int mode) {
    __shared__ __align__(16) unsigned Zs[N_BASES][4][4][ROWS + 1][4];  // 66 KB
    __shared__ int ticket;

    const int tid = threadIdx.x;
    const int wave = tid >> 6, lane = tid & 63;
    const int nb0 = blockIdx.x * ROWS;

    if (tid == 0) ticket = 0;
    __syncthreads();

    // phase-A frag coords: lane covers cols 2*lane, 2*lane+1
    const int lkk = lane >> 4, lq = (lane >> 2) & 3, lju = lane & 3;

    for (;;) {
        int row0 = 0;
        if (lane == 0) row0 = atomicAdd(&ticket, 1);
        const int row = __builtin_amdgcn_readfirstlane(row0);
        if (row >= ROWS) break;
        const int node = nb0 + row;
        int e = 0, end = 0;
        if (node < N) { e = row_ptr[node]; end = row_ptr[node + 1]; }

        floatx2 acc[N_BASES] = {};
        auto proc = [&](int2 m, unsigned g) {
            int ets = __builtin_amdgcn_readfirstlane(m.x >> 16);   // et wave-uniform
            float nv = __int_as_float(m.y);
            const float* cw = coef + ets * N_BASES;                // scalar loads
            floatx2 v;
            v.x = __uint_as_float(g << 16) * nv;
            v.y = __uint_as_float(g & 0xffff0000u) * nv;
#pragma unroll
            for (int b = 0; b < N_BASES; b++)
                acc[b] = v * cw[b] + acc[b];                       // v_pk_fma_f32
        };

        for (; e + 4 <= end; e += 4) {
            int2 m0 = edata[e], m1 = edata[e + 1], m2 = edata[e + 2], m3 = edata[e + 3];
            unsigned g0 = hb[(size_t)(m0.x & 0xffff) * 64 + lane];
            unsigned g1 = hb[(size_t)(m1.x & 0xffff) * 64 + lane];
            unsigned g2 = hb[(size_t)(m2.x & 0xffff) * 64 + lane];
            unsigned g3 = hb[(size_t)(m3.x & 0xffff) * 64 + lane];
            proc(m0, g0); proc(m1, g1); proc(m2, g2); proc(m3, g3);
        }
        for (; e < end; e++) {
            int2 m = edata[e];
            unsigned g = hb[(size_t)(m.x & 0xffff) * 64 + lane];
            proc(m, g);
        }

#pragma unroll
        for (int b = 0; b < N_BASES; b++) {
            unsigned lo = (unsigned)(unsigned short)bf16rn(acc[b].x);
            unsigned hi = (unsigned)(unsigned short)bf16rn(acc[b].y);
            Zs[b][lkk][lq][row][lju] = (hi << 16) | lo;    // zeros for node>=N too
        }
    }
    __syncthreads();

    // ---- phase B: wave owns t-tile tt=wave, m-tiles {0,1}
    const int q = lane >> 4, cc = lane & 15;
    const int tt = wave;
    floatx4 ac0 = {}, ac1 = {};

#pragma unroll 2
    for (int b = 0; b < N_BASES; b++) {
#pragma unroll
        for (int kk = 0; kk < 4; kk++) {
            bf16x8 a0 = *(const bf16x8*)&Zs[b][kk][q][cc][0];
            bf16x8 a1 = *(const bf16x8*)&Zs[b][kk][q][16 + cc][0];
            bf16x8 B = *(const bf16x8*)(Vf + (size_t)b * 16384 +
                                        ((size_t)(kk * 8 + tt) * 64 + lane) * 8);
            ac0 = __builtin_amdgcn_mfma_f32_16x16x32_bf16(a0, B, ac0, 0, 0, 0);
            ac1 = __builtin_amdgcn_mfma_f32_16x16x32_bf16(a1, B, ac1, 0, 0, 0);
        }
    }

    // ---- epilogue: C/D layout col = tt*16+cc, row(m) = mi*16 + q*4+i
    float bv = bias[tt * 16 + cc];
    if (mode == 0) {
        unsigned short* o = (unsigned short*)outp;
#pragma unroll
        for (int mi = 0; mi < 2; mi++) {
            const floatx4& c = mi ? ac1 : ac0;
#pragma unroll
            for (int i = 0; i < 4; i++) {
                int node = nb0 + mi * 16 + q * 4 + i;
                if (node < N) {
                    float v = fmaxf(c[i] + bv, 0.f);
                    o[(size_t)node * HD + tt * 16 + cc] = (unsigned short)bf16rn(v);
                }
            }
        }
    } else {
        float* o = (float*)outp;
#pragma unroll
        for (int mi = 0; mi < 2; mi++) {
            const floatx4& c = mi ? ac1 : ac0;
#pragma unroll
            for (int i = 0; i < 4; i++) {
                int node = nb0 + mi * 16 + q * 4 + i;
                if (node < N) o[(size_t)node * HD + tt * 16 + cc] = c[i] + bv;
            }
        }
    }
}

// ---------------- launch ----------------

extern "C" void kernel_launch(void* const* d_in, const int* in_sizes, int n_in,
                              void* d_out, int out_size, void* d_ws, size_t ws_size,
                              hipStream_t stream) {
    const float* h     = (const float*)d_in[0];
    const float* norm  = (const float*)d_in[1];
    const int*   src   = (const int*)d_in[2];
    const int*   dst   = (const int*)d_in[3];
    const int*   etype = (const int*)d_in[4];
    const float* V1    = (const float*)d_in[5];
    const float* coef1 = (const float*)d_in[6];
    const float* bias1 = (const float*)d_in[7];
    const float* V2    = (const float*)d_in[8];
    const float* coef2 = (const float*)d_in[9];
    const float* bias2 = (const float*)d_in[10];
    const int N = in_sizes[0] / HD;   // 50000
    const int E = in_sizes[2];        // 640000
    float* out = (float*)d_out;
    (void)n_in; (void)out_size; (void)ws_size;

    char* ws = (char*)d_ws;
    size_t off = 0;
    auto alloc = [&](size_t bytes) {
        void* p = ws + off;
        off += (bytes + 255) & ~(size_t)255;
        return p;
    };
    short*    Vf      = (short*)alloc((size_t)16 * 16384 * sizeof(short));   // 512 KB
    unsigned* hb      = (unsigned*)alloc((size_t)N * 64 * sizeof(unsigned)); // 12.8 MB
    unsigned* h1b     = (unsigned*)alloc((size_t)N * 64 * sizeof(unsigned)); // 12.8 MB
    int2*     edata   = (int2*)alloc((size_t)E * sizeof(int2));
    int*      cnt     = (int*)alloc((size_t)N * sizeof(int));
    int*      row_ptr = (int*)alloc((size_t)(N + 1) * sizeof(int));
    int*      cursor  = (int*)alloc((size_t)N * sizeof(int));
    int*      bsum    = (int*)alloc(256 * sizeof(int));

    const int nb = (N + SCAN_B - 1) / SCAN_B;                 // 49
    const int packBlocks = (N * 64 + 255) / 256;              // 12500
    const int vBlocks = 16;
    const int histBlocks = (E + 255) / 256;                   // 2500

    hipMemsetAsync(cnt, 0, (size_t)N * sizeof(int), stream);
    setup_fused<<<packBlocks + vBlocks + histBlocks, 256, 0, stream>>>(
        h, hb, N * 64, V1, V2, Vf, dst, E, cnt, packBlocks, vBlocks);
    scan_partial<<<nb, SCAN_B, 0, stream>>>(cnt, N, row_ptr, bsum);
    scan_fixup<<<(N + 255) / 256, 256, 0, stream>>>(row_ptr, bsum, nb, N, E, cursor);
    scatter_dst<<<(E + 255) / 256, 256, 0, stream>>>(dst, src, etype, norm, E, cursor, edata);

    const int tiles = (N + ROWS - 1) / ROWS;   // 1563

    // layer 1: h1b = bf16(relu(bias1 + Z @ V1))
    rgcn_tile<<<tiles, 512, 0, stream>>>(hb, edata, row_ptr, coef1, Vf, bias1, h1b, N, 0);
    // layer 2: out = bias2 + Z(h1b) @ V2
    rgcn_tile<<<tiles, 512, 0, stream>>>(h1b, edata, row_ptr, coef2, Vf + (size_t)8 * 16384,
                                         bias2, out, N, 1);
}